// Round 1
// baseline (1405.831 us; speedup 1.0000x reference)
//
#include <hip/hip_runtime.h>
#include <math.h>

// Problem constants (match reference): B=32, S=4096, H=1024, 2H=2048.
#define BB 32
#define SS 4096
#define HH 1024
#define TWOH 2048

// ---------------------------------------------------------------------------
// Kernel 1: v[b][d] = sum_h hidden[b][h] * W[h][d]
// Bias is dropped: hidden·bias is constant per batch row -> softmax invariant.
// Grid (dBlocks=4, hChunks=32): each block owns a 512-wide d-slice and a
// 32-wide h-window for ALL 32 batches -> W is read exactly once from HBM.
// Partials combined via atomicAdd (v zeroed by memsetAsync beforehand).
// ---------------------------------------------------------------------------
__global__ __launch_bounds__(256) void proj_kernel(
    const float* __restrict__ hidden,
    const float* __restrict__ W,
    float* __restrict__ v)
{
    __shared__ float lh[BB][32];  // hidden window: [b][hh]
    const int tid  = threadIdx.x;
    const int dblk = blockIdx.x;  // 0..3
    const int hc   = blockIdx.y;  // 0..31
    const int h0   = hc * 32;

    // Stage hidden[:, h0:h0+32] into LDS (1024 floats, 4 per thread).
    for (int i = tid; i < BB * 32; i += 256) {
        const int b = i >> 5, hh = i & 31;
        lh[b][hh] = hidden[b * HH + h0 + hh];
    }
    __syncthreads();

    const int d0 = dblk * 512 + tid * 2;   // 2 d-values per thread (float2)
    float2 acc[BB];
#pragma unroll
    for (int b = 0; b < BB; ++b) acc[b] = make_float2(0.f, 0.f);

    for (int hh = 0; hh < 32; ++hh) {
        const float2 w = *reinterpret_cast<const float2*>(&W[(size_t)(h0 + hh) * TWOH + d0]);
#pragma unroll
        for (int b = 0; b < BB; ++b) {
            const float hb = lh[b][hh];   // broadcast LDS read (conflict-free)
            acc[b].x += hb * w.x;
            acc[b].y += hb * w.y;
        }
    }
#pragma unroll
    for (int b = 0; b < BB; ++b) {
        atomicAdd(&v[b * TWOH + d0],     acc[b].x);
        atomicAdd(&v[b * TWOH + d0 + 1], acc[b].y);
    }
}

// ---------------------------------------------------------------------------
// Kernel 2: energies[b,s] = v[b] . enc[b,s]   (the 1.07 GB streaming pass)
// One wave per row, 16 rows per wave. v-fragment (32 floats/lane) held in
// registers and reused across the 16 rows. float4 loads, width-64 shfl reduce.
// 64 rows per block, all in the same batch b (64 | 4096).
// ---------------------------------------------------------------------------
__global__ __launch_bounds__(256) void energies_kernel(
    const float* __restrict__ enc,
    const float* __restrict__ v,
    float* __restrict__ energies)
{
    const int tid  = threadIdx.x;
    const int wave = tid >> 6;
    const int lane = tid & 63;
    const int rowBase = blockIdx.x * 64;       // 64 rows per block
    const int b = rowBase >> 12;               // rowBase / S, S = 4096

    // Load this lane's v fragment: elements j*256 + lane*4 .. +3, j = 0..7
    const float4* v4 = reinterpret_cast<const float4*>(v + (size_t)b * TWOH);
    float4 vf[8];
#pragma unroll
    for (int j = 0; j < 8; ++j) vf[j] = v4[j * 64 + lane];

    const int row0 = rowBase + wave * 16;
    for (int r = 0; r < 16; ++r) {
        const int row = row0 + r;
        const float4* e4 = reinterpret_cast<const float4*>(enc + (size_t)row * TWOH);
        float acc = 0.f;
#pragma unroll
        for (int j = 0; j < 8; ++j) {
            const float4 e = e4[j * 64 + lane];
            acc += vf[j].x * e.x + vf[j].y * e.y + vf[j].z * e.z + vf[j].w * e.w;
        }
#pragma unroll
        for (int m = 32; m >= 1; m >>= 1) acc += __shfl_xor(acc, m, 64);
        if (lane == 0) energies[row] = acc;
    }
}

// ---------------------------------------------------------------------------
// Kernel 3: in-place safe softmax over each row of 4096 (one block per b).
// 16 elements per thread kept in registers; block max + block sum reductions.
// ---------------------------------------------------------------------------
__global__ __launch_bounds__(256) void softmax_kernel(float* __restrict__ out)
{
    const int b   = blockIdx.x;
    const int tid = threadIdx.x;
    float* row = out + (size_t)b * SS;

    float x[16];
#pragma unroll
    for (int k = 0; k < 16; ++k) x[k] = row[tid + k * 256];

    float mx = -INFINITY;
#pragma unroll
    for (int k = 0; k < 16; ++k) mx = fmaxf(mx, x[k]);

    __shared__ float red[8];
    const int wave = tid >> 6, lane = tid & 63;
#pragma unroll
    for (int m = 32; m >= 1; m >>= 1) mx = fmaxf(mx, __shfl_xor(mx, m, 64));
    if (lane == 0) red[wave] = mx;
    __syncthreads();
    mx = fmaxf(fmaxf(red[0], red[1]), fmaxf(red[2], red[3]));

    float sum = 0.f;
#pragma unroll
    for (int k = 0; k < 16; ++k) { x[k] = __expf(x[k] - mx); sum += x[k]; }
#pragma unroll
    for (int m = 32; m >= 1; m >>= 1) sum += __shfl_xor(sum, m, 64);
    if (lane == 0) red[4 + wave] = sum;
    __syncthreads();
    sum = red[4] + red[5] + red[6] + red[7];

    const float inv = 1.f / sum;
#pragma unroll
    for (int k = 0; k < 16; ++k) row[tid + k * 256] = x[k] * inv;
}

// ---------------------------------------------------------------------------
extern "C" void kernel_launch(void* const* d_in, const int* in_sizes, int n_in,
                              void* d_out, int out_size, void* d_ws, size_t ws_size,
                              hipStream_t stream)
{
    const float* hidden = (const float*)d_in[0];   // [B, H]
    const float* enc    = (const float*)d_in[1];   // [B, S, 2H]
    const float* W      = (const float*)d_in[2];   // [H, 2H]
    // d_in[3] = bias: mathematically irrelevant after softmax (constant per row)

    float* v   = (float*)d_ws;    // [B, 2H] = 256 KB scratch
    float* out = (float*)d_out;   // [B, 1, S] fp32; used as energies staging too

    // ws is re-poisoned (0xAA) before every timed launch -> zero v each call.
    hipMemsetAsync(d_ws, 0, (size_t)BB * TWOH * sizeof(float), stream);

    proj_kernel<<<dim3(4, 32), 256, 0, stream>>>(hidden, W, v);
    energies_kernel<<<dim3(BB * SS / 64), 256, 0, stream>>>(enc, v, out);
    softmax_kernel<<<dim3(BB), 256, 0, stream>>>(out);
}

// Round 2
// 1365.428 us; speedup vs baseline: 1.0296x; 1.0296x over previous
//
#include <hip/hip_runtime.h>
#include <math.h>

// Problem constants: B=32, S=4096, H=1024, 2H=2048.
#define BB 32
#define SS 4096
#define HH 1024
#define TWOH 2048
#define PPARTS 16        // h-chunks for atomic-free projection
#define HCHUNK 64        // HH / PPARTS

// ---------------------------------------------------------------------------
// Kernel 1: partial projection, atomic-free.
//   v_part[hc][b][d] = sum_{h in chunk hc} hidden[b][h] * W[h][d]
// Bias dropped: hidden·bias is constant per row -> softmax invariant.
// Grid (4 d-slices x 16 h-chunks) = 64 blocks; W read exactly once (8 MB).
// Every byte of v_part is written -> no memset needed despite 0xAA poison.
// ---------------------------------------------------------------------------
__global__ __launch_bounds__(256) void proj_kernel(
    const float* __restrict__ hidden,
    const float* __restrict__ W,
    float* __restrict__ v_part)
{
    __shared__ float lh[BB][HCHUNK];   // hidden window [b][hh]
    const int tid  = threadIdx.x;
    const int dblk = blockIdx.x;       // 0..3  (512 d-cols each)
    const int hc   = blockIdx.y;       // 0..15 (64 h each)
    const int h0   = hc * HCHUNK;

    // Stage hidden[:, h0:h0+64) into LDS (2048 floats).
    for (int i = tid; i < BB * HCHUNK; i += 256) {
        const int b = i >> 6, hh = i & 63;
        lh[b][hh] = hidden[b * HH + h0 + hh];
    }
    __syncthreads();

    const int d0 = dblk * 512 + tid * 2;   // float2 per thread
    float2 acc[BB];
#pragma unroll
    for (int b = 0; b < BB; ++b) acc[b] = make_float2(0.f, 0.f);

    for (int hh = 0; hh < HCHUNK; ++hh) {
        const float2 w = *reinterpret_cast<const float2*>(
            &W[(size_t)(h0 + hh) * TWOH + d0]);
#pragma unroll
        for (int b = 0; b < BB; ++b) {
            const float hb = lh[b][hh];   // LDS broadcast, conflict-free
            acc[b].x += hb * w.x;
            acc[b].y += hb * w.y;
        }
    }

    float* dst = v_part + (size_t)hc * BB * TWOH;
#pragma unroll
    for (int b = 0; b < BB; ++b)
        *reinterpret_cast<float2*>(&dst[b * TWOH + d0]) = acc[b];
}

// ---------------------------------------------------------------------------
// Kernel 2: v[b][d] = sum_p v_part[p][b][d]   (4 MB read, ~2 us)
// ---------------------------------------------------------------------------
__global__ __launch_bounds__(256) void reduce_kernel(
    const float* __restrict__ v_part,
    float* __restrict__ v)
{
    const int i = (blockIdx.x * 256 + threadIdx.x) * 4;  // 65536 floats total
    float4 s = make_float4(0.f, 0.f, 0.f, 0.f);
#pragma unroll
    for (int p = 0; p < PPARTS; ++p) {
        const float4 t = *reinterpret_cast<const float4*>(&v_part[(size_t)p * BB * TWOH + i]);
        s.x += t.x; s.y += t.y; s.z += t.z; s.w += t.w;
    }
    *reinterpret_cast<float4*>(&v[i]) = s;
}

// ---------------------------------------------------------------------------
// Kernel 3: energies[b,s] = v[b] . enc[b,s]   (the 1.07 GB streaming pass)
// One wave per row, 16 rows/wave, v-fragment register-resident.
// 2-row software pipeline: next row's 8 float4 loads issued before the
// current row's shfl-reduce chain, keeping loads in flight.
// ---------------------------------------------------------------------------
__global__ __launch_bounds__(256) void energies_kernel(
    const float* __restrict__ enc,
    const float* __restrict__ v,
    float* __restrict__ energies)
{
    const int tid  = threadIdx.x;
    const int wave = tid >> 6;
    const int lane = tid & 63;
    const int rowBase = blockIdx.x * 64;   // 64 rows per block
    const int b = rowBase >> 12;           // rowBase / S

    const float4* v4 = reinterpret_cast<const float4*>(v + (size_t)b * TWOH);
    float4 vf[8];
#pragma unroll
    for (int j = 0; j < 8; ++j) vf[j] = v4[j * 64 + lane];

    const int row0 = rowBase + wave * 16;

    float4 cur[8];
    {
        const float4* e4 = reinterpret_cast<const float4*>(enc + (size_t)row0 * TWOH);
#pragma unroll
        for (int j = 0; j < 8; ++j) cur[j] = e4[j * 64 + lane];
    }

    for (int r = 0; r < 16; ++r) {
        float4 nxt[8];
        if (r < 15) {
            const float4* n4 = reinterpret_cast<const float4*>(
                enc + (size_t)(row0 + r + 1) * TWOH);
#pragma unroll
            for (int j = 0; j < 8; ++j) nxt[j] = n4[j * 64 + lane];
        }

        float acc = 0.f;
#pragma unroll
        for (int j = 0; j < 8; ++j)
            acc += vf[j].x * cur[j].x + vf[j].y * cur[j].y
                 + vf[j].z * cur[j].z + vf[j].w * cur[j].w;
#pragma unroll
        for (int m = 32; m >= 1; m >>= 1) acc += __shfl_xor(acc, m, 64);
        if (lane == 0) energies[row0 + r] = acc;

        if (r < 15) {
#pragma unroll
            for (int j = 0; j < 8; ++j) cur[j] = nxt[j];
        }
    }
}

// ---------------------------------------------------------------------------
// Kernel 4: in-place safe softmax over each row of 4096 (one block per b).
// ---------------------------------------------------------------------------
__global__ __launch_bounds__(256) void softmax_kernel(float* __restrict__ out)
{
    const int b   = blockIdx.x;
    const int tid = threadIdx.x;
    float* row = out + (size_t)b * SS;

    float x[16];
#pragma unroll
    for (int k = 0; k < 16; ++k) x[k] = row[tid + k * 256];

    float mx = -INFINITY;
#pragma unroll
    for (int k = 0; k < 16; ++k) mx = fmaxf(mx, x[k]);

    __shared__ float red[8];
    const int wave = tid >> 6, lane = tid & 63;
#pragma unroll
    for (int m = 32; m >= 1; m >>= 1) mx = fmaxf(mx, __shfl_xor(mx, m, 64));
    if (lane == 0) red[wave] = mx;
    __syncthreads();
    mx = fmaxf(fmaxf(red[0], red[1]), fmaxf(red[2], red[3]));

    float sum = 0.f;
#pragma unroll
    for (int k = 0; k < 16; ++k) { x[k] = __expf(x[k] - mx); sum += x[k]; }
#pragma unroll
    for (int m = 32; m >= 1; m >>= 1) sum += __shfl_xor(sum, m, 64);
    if (lane == 0) red[4 + wave] = sum;
    __syncthreads();
    sum = red[4] + red[5] + red[6] + red[7];

    const float inv = 1.f / sum;
#pragma unroll
    for (int k = 0; k < 16; ++k) row[tid + k * 256] = x[k] * inv;
}

// ---------------------------------------------------------------------------
extern "C" void kernel_launch(void* const* d_in, const int* in_sizes, int n_in,
                              void* d_out, int out_size, void* d_ws, size_t ws_size,
                              hipStream_t stream)
{
    const float* hidden = (const float*)d_in[0];   // [B, H]
    const float* enc    = (const float*)d_in[1];   // [B, S, 2H]
    const float* W      = (const float*)d_in[2];   // [H, 2H]
    // d_in[3] = bias: softmax-invariant, dropped.

    float* v_part = (float*)d_ws;                              // 16*32*2048 f32 = 4 MB
    float* v      = v_part + (size_t)PPARTS * BB * TWOH;       // 32*2048 f32 = 256 KB
    float* out    = (float*)d_out;                             // [B,1,S] fp32

    proj_kernel   <<<dim3(4, PPARTS), 256, 0, stream>>>(hidden, W, v_part);
    reduce_kernel <<<dim3(64),        256, 0, stream>>>(v_part, v);
    energies_kernel<<<dim3(BB * SS / 64), 256, 0, stream>>>(enc, v, out);
    softmax_kernel<<<dim3(BB),        256, 0, stream>>>(out);
}